// Round 9
// baseline (167.225 us; speedup 1.0000x reference)
//
#include <hip/hip_runtime.h>
#include <hip/hip_bf16.h>
#include <hip/hip_fp16.h>

typedef __attribute__((ext_vector_type(8))) short short8;
typedef __attribute__((ext_vector_type(4))) short s16x4;
typedef __attribute__((ext_vector_type(4))) float f32x4;

#define BN 4
#define PN 1024
#define NN 16
#define C1N 64
#define C2N 64
#define KN 13
#define AN 12
#define KDIM 9984   // C1N*KN*AN, kk = k*768 + c*12 + a  (k=12 slice at 9216+)
#define NDIM 768    // C2N*AN
#define MDIM 4096   // BN*PN
#define NSPLIT 6
#define KLEN 1664   // KDIM/NSPLIT
#define BK 64
#define NTI 26      // KLEN/BK
#define BM 256      // GEMM block tile M
#define BNT 128     // GEMM block tile N

__device__ inline unsigned short f2bf(float x){
    unsigned int u = __float_as_uint(x);
    unsigned int r = (u + 0x7fffu + ((u >> 16) & 1u)) >> 16;
    return (unsigned short)r;
}
__device__ inline f32x4 bf4_to_f(s16x4 h){
    f32x4 r;
    r[0] = __uint_as_float(((unsigned)(unsigned short)h[0]) << 16);
    r[1] = __uint_as_float(((unsigned)(unsigned short)h[1]) << 16);
    r[2] = __uint_as_float(((unsigned)(unsigned short)h[2]) << 16);
    r[3] = __uint_as_float(((unsigned)(unsigned short)h[3]) << 16);
    return r;
}

// async global->LDS, 16B per lane. LDS dest = wave-uniform base + lane*16.
__device__ __forceinline__ void gload16(const unsigned short* g, unsigned short* l){
    __builtin_amdgcn_global_load_lds(
        (const __attribute__((address_space(1))) unsigned int*)(unsigned long long)(uintptr_t)g,
        (__attribute__((address_space(3))) unsigned int*)(unsigned int)(uintptr_t)l,
        16, 0, 0);
}

// ================= Kernel 1: fused prep (interw | beff | tr) =================
// blocks [0,192): inter_w softmax; [192,2688): W_eff->Bm; [2688,5760): fm->Am k=12 slice
__global__ __launch_bounds__(256) void k_prep(const int* __restrict__ nbr,
                                              const float* __restrict__ vert,
                                              const float* __restrict__ vs,
                                              const float* __restrict__ W,
                                              const int* __restrict__ idx_map,
                                              const int* __restrict__ tiv,
                                              const int* __restrict__ tir,
                                              const float* __restrict__ fm,
                                              float* __restrict__ iw,
                                              unsigned short* __restrict__ Bm,
                                              unsigned short* __restrict__ Am)
{
    int bid = blockIdx.x;
    if (bid < 192){
        // ---- interw: thread per (point, a) ----
        int t = bid * 256 + threadIdx.x;      // < 49152
        int pt = t / AN, a = t - pt * AN;
        int b = pt >> 10;
        float sx = vs[a*3+0], sy = vs[a*3+1], sz = vs[a*3+2];
        float sn = sqrtf(sx*sx + sy*sy + sz*sz);
        float si = 1.0f / fmaxf(sn, 1e-12f);
        sx *= si; sy *= si; sz *= si;
        float vx = vert[pt*3+0], vy = vert[pt*3+1], vz = vert[pt*3+2];
        float tt[NN];
        float mx = -1e30f;
        #pragma unroll
        for (int n = 0; n < NN; n++){
            int g = (b << 10) + nbr[pt*NN + n];
            float dx = vert[g*3+0] - vx;
            float dy = vert[g*3+1] - vy;
            float dz = vert[g*3+2] - vz;
            float nr = sqrtf(dx*dx + dy*dy + dz*dz);
            float inv = 1.0f / fmaxf(nr, 1e-12f);
            tt[n] = (dx*sx + dy*sy + dz*sz) * inv;
            mx = fmaxf(mx, tt[n]);
        }
        float s = 0.0f;
        #pragma unroll
        for (int n = 0; n < NN; n++){ tt[n] = expf(tt[n] - mx); s += tt[n]; }
        float inv = 1.0f / s;
        float* dst = iw + (size_t)t * NN;
        #pragma unroll
        for (int q = 0; q < 4; q++){
            float4 v = make_float4(tt[q*4]*inv, tt[q*4+1]*inv, tt[q*4+2]*inv, tt[q*4+3]*inv);
            *(float4*)(dst + q*4) = v;
        }
    } else if (bid < 2688){
        // ---- beff: thread per (d,r,k,c) ----
        int t = (bid - 192) * 256 + threadIdx.x;   // < 638976
        int c = t & 63;
        int rest = t >> 6;          // < 9984
        int k = rest % KN;
        int rest2 = rest / KN;      // < 768
        int r = rest2 % AN;
        int d = rest2 / AN;
        int tv = tiv[r*KN + k];
        const float* wrow = W + (size_t)((d << 6) + c) * 36;
        s16x4 v0, v1, v2;
        #pragma unroll
        for (int a = 0; a < AN; a++){
            int s = idx_map[tv*AN + tir[r*AN + a]];
            unsigned short h = f2bf(wrow[s]);
            if (a < 4) v0[a] = (short)h;
            else if (a < 8) v1[a-4] = (short)h;
            else v2[a-8] = (short)h;
        }
        unsigned short* dst = Bm + ((size_t)(d*AN + r) * KDIM + k*768 + c*AN);
        s16x4* d4 = (s16x4*)dst;
        d4[0] = v0; d4[1] = v1; d4[2] = v2;
    } else {
        // ---- tr: fm -> bf16 own-feature slice Am[m][9216 + c*12 + a] ----
        int t = (bid - 2688) * 256 + threadIdx.x;     // < 786432
        int a4 = t % 3;
        int rest = t / 3;                            // (b*64 + c)*1024 + p
        int p = rest & 1023;
        int bc = rest >> 10;
        int c = bc & 63, b = bc >> 6;
        float4 v = *(const float4*)(fm + (size_t)rest * 12 + a4*4);
        s16x4 h;
        h[0] = (short)f2bf(v.x); h[1] = (short)f2bf(v.y);
        h[2] = (short)f2bf(v.z); h[3] = (short)f2bf(v.w);
        int m = (b << 10) + p;
        *(s16x4*)(Am + (size_t)m * KDIM + 9216 + c*12 + a4*4) = h;
    }
}

// ---------------- Kernel 3: new_feat k=0..11 -> Am[m][k*768+c*12+a] ----------------
// 2 waves per point (k-halves), lane = channel c. Gathers = contiguous 1536B bf16 rows
// from the k=12 slice. acc 72 VGPR.
__global__ __launch_bounds__(256) void k_newfeat(const int* __restrict__ nbr,
                                                 const float* __restrict__ iw,
                                                 unsigned short* Am)
{
    __shared__ int   nbs_s[2][NN];
    __shared__ float iwT_s[2][NN][AN];      // [point-in-block][n][k]
    int t = threadIdx.x;
    int w = t >> 6, lane = t & 63;
    int pw = w >> 1, khalf = w & 1;
    int m = blockIdx.x * 2 + pw;            // point id < 4096
    int b = m >> 10;

    if (khalf == 0){
        if (lane < NN) nbs_s[pw][lane] = nbr[m*NN + lane];
        #pragma unroll
        for (int i = 0; i < 3; i++){
            int idx = lane + i*64;              // < 192
            int a = idx >> 4, n = idx & 15;     // iw layout [a][n]
            iwT_s[pw][n][a] = iw[(size_t)m * (AN*NN) + idx];
        }
    }
    __syncthreads();

    f32x4 acc[6][3];
    #pragma unroll
    for (int k = 0; k < 6; k++)
        #pragma unroll
        for (int q = 0; q < 3; q++) acc[k][q] = (f32x4){0.f,0.f,0.f,0.f};

    int kb = khalf * 6;
    const unsigned short* slice = Am + 9216 + (size_t)lane * AN;

    #pragma unroll 2
    for (int n = 0; n < NN; n++){
        int mn = (b << 10) + nbs_s[pw][n];
        const unsigned short* src = slice + (size_t)mn * KDIM;
        s16x4 u0 = *(const s16x4*)(src);
        s16x4 u1 = *(const s16x4*)(src + 4);
        s16x4 u2 = *(const s16x4*)(src + 8);
        f32x4 v0 = bf4_to_f(u0), v1 = bf4_to_f(u1), v2 = bf4_to_f(u2);
        #pragma unroll
        for (int k = 0; k < 6; k++){
            float wv = iwT_s[pw][n][kb + k];
            acc[k][0] += v0 * wv;
            acc[k][1] += v1 * wv;
            acc[k][2] += v2 * wv;
        }
    }

    unsigned short* dst = Am + (size_t)m * KDIM + lane * AN;
    #pragma unroll
    for (int k = 0; k < 6; k++){
        s16x4 h0, h1, h2;
        #pragma unroll
        for (int j = 0; j < 4; j++){
            h0[j] = (short)f2bf(acc[k][0][j]);
            h1[j] = (short)f2bf(acc[k][1][j]);
            h2[j] = (short)f2bf(acc[k][2][j]);
        }
        s16x4* o = (s16x4*)(dst + (kb + k)*768);
        o[0] = h0; o[1] = h1; o[2] = h2;
    }
}

// ---------------- Kernel 4: GEMM 256x128, dbuf BK=64, counted vmcnt (T4) ----------------
// 4 waves (2Mx2N), per-wave tile 128x64 (acc 8x4) -> LDS bytes/FLOP 366 vs 488 at 64x64:
// MFMA-issue becomes the binding resource. Sync skeleton identical to R8 (proven):
// barrier -> ISSUE(s+1) -> vmcnt(12) -> barrier -> BODY(s). 12 loads/batch stay in
// flight across the whole body; vmcnt never drains to 0 in the loop.
// T2 swizzle: source chunk ch^(row&7), same XOR on read (involution; measured 0 conflicts).
__global__ __launch_bounds__(256, 1) void k_gemm(const unsigned short* __restrict__ Am,
                                                 const unsigned short* __restrict__ Bm,
                                                 __half* __restrict__ part)
{
    __shared__ unsigned short Al[2][BM*BK];    // 2 x 32 KB
    __shared__ unsigned short Bl[2][BNT*BK];   // 2 x 16 KB
    int t = threadIdx.x;
    int lane = t & 63, w = t >> 6;
    int wr = w >> 1, wc = w & 1;
    int l15 = lane & 15;
    int kofs = (lane >> 4) * 8;
    int m0 = blockIdx.x * BM, n0 = blockIdx.y * BNT;
    int kbase = blockIdx.z * KLEN;

    // staging chunks: A: g = i*256+t (i<8); B: g = i*256+t (i<4). row=g>>3, ch=g&7.
    const unsigned short* gA[8];
    const unsigned short* gB[4];
    int lofsA[8], lofsB[4];
    #pragma unroll
    for (int i = 0; i < 8; i++){
        int g = i*256 + t;
        int row = g >> 3, ch = g & 7;
        int sch = ch ^ (row & 7);           // pre-swizzled source chunk (involution)
        gA[i] = Am + (size_t)(m0 + row) * KDIM + kbase + sch*8;
        lofsA[i] = g * 8;
    }
    #pragma unroll
    for (int i = 0; i < 4; i++){
        int g = i*256 + t;
        int row = g >> 3, ch = g & 7;
        int sch = ch ^ (row & 7);
        gB[i] = Bm + (size_t)(n0 + row) * KDIM + kbase + sch*8;
        lofsB[i] = g * 8;
    }

    f32x4 acc[8][4] = {};

#define ISSUE(S,KK) {                                                    \
        _Pragma("unroll")                                                \
        for (int i = 0; i < 8; i++) gload16(gA[i] + (KK), &Al[(S)&1][lofsA[i]]); \
        _Pragma("unroll")                                                \
        for (int i = 0; i < 4; i++) gload16(gB[i] + (KK), &Bl[(S)&1][lofsB[i]]); }

#define BODY(S) { const int cur_ = (S) & 1;                              \
        _Pragma("unroll")                                                \
        for (int kh = 0; kh < 2; kh++){                                  \
            int cc = kh*4 + (kofs >> 3);                                 \
            short8 af[8], bf[4];                                         \
            _Pragma("unroll")                                            \
            for (int i = 0; i < 8; i++){                                 \
                int ra = wr*128 + i*16 + l15;                            \
                af[i] = *(const short8*)&Al[cur_][ra*BK + ((cc ^ (ra & 7)) * 8)]; \
            }                                                            \
            _Pragma("unroll")                                            \
            for (int j = 0; j < 4; j++){                                 \
                int rb = wc*64 + j*16 + l15;                             \
                bf[j] = *(const short8*)&Bl[cur_][rb*BK + ((cc ^ (rb & 7)) * 8)]; \
            }                                                            \
            _Pragma("unroll")                                            \
            for (int i = 0; i < 8; i++){                                 \
                _Pragma("unroll")                                        \
                for (int j = 0; j < 4; j++)                              \
                    acc[i][j] = __builtin_amdgcn_mfma_f32_16x16x32_bf16(af[i], bf[j], acc[i][j], 0, 0, 0); \
            }                                                            \
        } }

    // prologue: stage tile 0 into buffer 0
    ISSUE(0, 0);

    for (int s = 0; s < NTI; ++s){
        __builtin_amdgcn_s_barrier();            // WAR: all waves done reading buf[(s+1)&1]
        if (s + 1 < NTI) ISSUE(s + 1, (s + 1) * BK);
        if (s + 1 < NTI) { asm volatile("s_waitcnt vmcnt(12)" ::: "memory"); }
        else             { asm volatile("s_waitcnt vmcnt(0)" ::: "memory"); }
        __builtin_amdgcn_s_barrier();            // RAW: every wave's batch-s loads landed
        BODY(s);
    }
#undef ISSUE
#undef BODY

    // epilogue: fp16 partials. C/D layout col=lane&15, row=(lane>>4)*4+q [m89-verified]
    __half* pp = part + (size_t)blockIdx.z * ((size_t)MDIM * NDIM);
    #pragma unroll
    for (int i = 0; i < 8; i++){
        #pragma unroll
        for (int j = 0; j < 4; j++){
            int col = n0 + wc*64 + j*16 + l15;
            #pragma unroll
            for (int q = 0; q < 4; q++){
                int row = m0 + wr*128 + i*16 + (lane >> 4)*4 + q;
                pp[(size_t)row * NDIM + col] = __float2half(acc[i][j][q]);
            }
        }
    }
}

// ---------------- Kernel 5: split-K reduce (fp16 partials) + scatter to bdpr ----------------
__global__ __launch_bounds__(256) void k_reduce(const __half* __restrict__ part,
                                                float* __restrict__ out)
{
    int t = blockIdx.x * 256 + threadIdx.x;        // per float4: MDIM*NDIM/4
    if (t >= MDIM * (NDIM/4)) return;
    int m = t / (NDIM/4);
    int n4 = (t - m * (NDIM/4)) * 4;
    f32x4 s = {};
    #pragma unroll
    for (int z = 0; z < NSPLIT; z++){
        const __half2* pz = (const __half2*)(part + (size_t)z * ((size_t)MDIM * NDIM) + (size_t)m * NDIM + n4);
        float2 a = __half22float2(pz[0]);
        float2 b = __half22float2(pz[1]);
        s[0] += a.x; s[1] += a.y; s[2] += b.x; s[3] += b.y;
    }
    int b = m >> 10, p = m & 1023;
    int d = n4 / AN, r = n4 - d*AN;    // r in {0,4,8}: never crosses d within 4
    *(f32x4*)(out + ((size_t)((b << 6) + d) * PN + p) * AN + r) = s;
}

extern "C" void kernel_launch(void* const* d_in, const int* in_sizes, int n_in,
                              void* d_out, int out_size, void* d_ws, size_t ws_size,
                              hipStream_t stream)
{
    const int*   nbr     = (const int*)  d_in[0];
    const float* vert    = (const float*)d_in[1];
    const float* fm      = (const float*)d_in[2];
    const float* W       = (const float*)d_in[3];
    const float* vs      = (const float*)d_in[4];
    const int*   idx_map = (const int*)  d_in[5];
    const int*   tiv     = (const int*)  d_in[6];
    const int*   tir     = (const int*)  d_in[7];
    float* out = (float*)d_out;

    char* ws = (char*)d_ws;
    float*          iw   = (float*)ws;                                  // 3,145,728 B
    unsigned short* Bm   = (unsigned short*)(ws + 3145728);             // 15,335,424 B
    unsigned short* Am   = (unsigned short*)(ws + 18481152);            // 81,788,928 B
    __half*         part = (__half*)(ws + 100270080);                   // 37,748,736 B (6 x fp16)

    k_prep   <<<5760, 256, 0, stream>>>(nbr, vert, vs, W, idx_map, tiv, tir, fm, iw, Bm, Am);
    k_newfeat<<<MDIM/2, 256, 0, stream>>>(nbr, iw, Am);
    dim3 g(MDIM/BM, NDIM/BNT, NSPLIT);
    k_gemm   <<<g, 256, 0, stream>>>(Am, Bm, part);
    k_reduce <<<(MDIM*(NDIM/4))/256, 256, 0, stream>>>(part, out);
}

// Round 10
// 119.247 us; speedup vs baseline: 1.4023x; 1.4023x over previous
//
#include <hip/hip_runtime.h>
#include <hip/hip_bf16.h>
#include <hip/hip_fp16.h>

typedef __attribute__((ext_vector_type(8))) short short8;
typedef __attribute__((ext_vector_type(4))) short s16x4;
typedef __attribute__((ext_vector_type(4))) float f32x4;

#define BN 4
#define PN 1024
#define NN 16
#define C1N 64
#define C2N 64
#define KN 13
#define AN 12
#define KDIM 9984   // C1N*KN*AN, kk = k*768 + c*12 + a  (k=12 slice at 9216+)
#define NDIM 768    // C2N*AN
#define MDIM 4096   // BN*PN
#define NSPLIT 5    // uneven K split: 32,31,31,31,31 steps of BK=64 (total 156)
#define BK 64
#define BM 256      // GEMM block tile M
#define BNT 256     // GEMM block tile N

__device__ inline unsigned short f2bf(float x){
    unsigned int u = __float_as_uint(x);
    unsigned int r = (u + 0x7fffu + ((u >> 16) & 1u)) >> 16;
    return (unsigned short)r;
}
__device__ inline f32x4 bf4_to_f(s16x4 h){
    f32x4 r;
    r[0] = __uint_as_float(((unsigned)(unsigned short)h[0]) << 16);
    r[1] = __uint_as_float(((unsigned)(unsigned short)h[1]) << 16);
    r[2] = __uint_as_float(((unsigned)(unsigned short)h[2]) << 16);
    r[3] = __uint_as_float(((unsigned)(unsigned short)h[3]) << 16);
    return r;
}

// async global->LDS, 16B per lane. LDS dest = wave-uniform base + lane*16.
__device__ __forceinline__ void gload16(const unsigned short* g, unsigned short* l){
    __builtin_amdgcn_global_load_lds(
        (const __attribute__((address_space(1))) unsigned int*)(unsigned long long)(uintptr_t)g,
        (__attribute__((address_space(3))) unsigned int*)(unsigned int)(uintptr_t)l,
        16, 0, 0);
}

// ================= Kernel 1: fused prep (interw | beff | tr) =================
// blocks [0,192): inter_w softmax; [192,2688): W_eff->Bm; [2688,5760): fm->Am k=12 slice
__global__ __launch_bounds__(256) void k_prep(const int* __restrict__ nbr,
                                              const float* __restrict__ vert,
                                              const float* __restrict__ vs,
                                              const float* __restrict__ W,
                                              const int* __restrict__ idx_map,
                                              const int* __restrict__ tiv,
                                              const int* __restrict__ tir,
                                              const float* __restrict__ fm,
                                              float* __restrict__ iw,
                                              unsigned short* __restrict__ Bm,
                                              unsigned short* __restrict__ Am)
{
    int bid = blockIdx.x;
    if (bid < 192){
        // ---- interw: thread per (point, a) ----
        int t = bid * 256 + threadIdx.x;      // < 49152
        int pt = t / AN, a = t - pt * AN;
        int b = pt >> 10;
        float sx = vs[a*3+0], sy = vs[a*3+1], sz = vs[a*3+2];
        float sn = sqrtf(sx*sx + sy*sy + sz*sz);
        float si = 1.0f / fmaxf(sn, 1e-12f);
        sx *= si; sy *= si; sz *= si;
        float vx = vert[pt*3+0], vy = vert[pt*3+1], vz = vert[pt*3+2];
        float tt[NN];
        float mx = -1e30f;
        #pragma unroll
        for (int n = 0; n < NN; n++){
            int g = (b << 10) + nbr[pt*NN + n];
            float dx = vert[g*3+0] - vx;
            float dy = vert[g*3+1] - vy;
            float dz = vert[g*3+2] - vz;
            float nr = sqrtf(dx*dx + dy*dy + dz*dz);
            float inv = 1.0f / fmaxf(nr, 1e-12f);
            tt[n] = (dx*sx + dy*sy + dz*sz) * inv;
            mx = fmaxf(mx, tt[n]);
        }
        float s = 0.0f;
        #pragma unroll
        for (int n = 0; n < NN; n++){ tt[n] = expf(tt[n] - mx); s += tt[n]; }
        float inv = 1.0f / s;
        float* dst = iw + (size_t)t * NN;
        #pragma unroll
        for (int q = 0; q < 4; q++){
            float4 v = make_float4(tt[q*4]*inv, tt[q*4+1]*inv, tt[q*4+2]*inv, tt[q*4+3]*inv);
            *(float4*)(dst + q*4) = v;
        }
    } else if (bid < 2688){
        // ---- beff: thread per (d,r,k,c) ----
        int t = (bid - 192) * 256 + threadIdx.x;   // < 638976
        int c = t & 63;
        int rest = t >> 6;          // < 9984
        int k = rest % KN;
        int rest2 = rest / KN;      // < 768
        int r = rest2 % AN;
        int d = rest2 / AN;
        int tv = tiv[r*KN + k];
        const float* wrow = W + (size_t)((d << 6) + c) * 36;
        s16x4 v0, v1, v2;
        #pragma unroll
        for (int a = 0; a < AN; a++){
            int s = idx_map[tv*AN + tir[r*AN + a]];
            unsigned short h = f2bf(wrow[s]);
            if (a < 4) v0[a] = (short)h;
            else if (a < 8) v1[a-4] = (short)h;
            else v2[a-8] = (short)h;
        }
        unsigned short* dst = Bm + ((size_t)(d*AN + r) * KDIM + k*768 + c*AN);
        s16x4* d4 = (s16x4*)dst;
        d4[0] = v0; d4[1] = v1; d4[2] = v2;
    } else {
        // ---- tr: fm -> bf16 own-feature slice Am[m][9216 + c*12 + a] ----
        int t = (bid - 2688) * 256 + threadIdx.x;     // < 786432
        int a4 = t % 3;
        int rest = t / 3;                            // (b*64 + c)*1024 + p
        int p = rest & 1023;
        int bc = rest >> 10;
        int c = bc & 63, b = bc >> 6;
        float4 v = *(const float4*)(fm + (size_t)rest * 12 + a4*4);
        s16x4 h;
        h[0] = (short)f2bf(v.x); h[1] = (short)f2bf(v.y);
        h[2] = (short)f2bf(v.z); h[3] = (short)f2bf(v.w);
        int m = (b << 10) + p;
        *(s16x4*)(Am + (size_t)m * KDIM + 9216 + c*12 + a4*4) = h;
    }
}

// ---------------- Kernel 3: new_feat k=0..11 -> Am[m][k*768+c*12+a] ----------------
// 2 waves per point (k-halves), lane = channel c. Gathers = contiguous 1536B bf16 rows
// from the k=12 slice. acc 72 VGPR.
__global__ __launch_bounds__(256) void k_newfeat(const int* __restrict__ nbr,
                                                 const float* __restrict__ iw,
                                                 unsigned short* Am)
{
    __shared__ int   nbs_s[2][NN];
    __shared__ float iwT_s[2][NN][AN];      // [point-in-block][n][k]
    int t = threadIdx.x;
    int w = t >> 6, lane = t & 63;
    int pw = w >> 1, khalf = w & 1;
    int m = blockIdx.x * 2 + pw;            // point id < 4096
    int b = m >> 10;

    if (khalf == 0){
        if (lane < NN) nbs_s[pw][lane] = nbr[m*NN + lane];
        #pragma unroll
        for (int i = 0; i < 3; i++){
            int idx = lane + i*64;              // < 192
            int a = idx >> 4, n = idx & 15;     // iw layout [a][n]
            iwT_s[pw][n][a] = iw[(size_t)m * (AN*NN) + idx];
        }
    }
    __syncthreads();

    f32x4 acc[6][3];
    #pragma unroll
    for (int k = 0; k < 6; k++)
        #pragma unroll
        for (int q = 0; q < 3; q++) acc[k][q] = (f32x4){0.f,0.f,0.f,0.f};

    int kb = khalf * 6;
    const unsigned short* slice = Am + 9216 + (size_t)lane * AN;

    #pragma unroll 2
    for (int n = 0; n < NN; n++){
        int mn = (b << 10) + nbs_s[pw][n];
        const unsigned short* src = slice + (size_t)mn * KDIM;
        s16x4 u0 = *(const s16x4*)(src);
        s16x4 u1 = *(const s16x4*)(src + 4);
        s16x4 u2 = *(const s16x4*)(src + 8);
        f32x4 v0 = bf4_to_f(u0), v1 = bf4_to_f(u1), v2 = bf4_to_f(u2);
        #pragma unroll
        for (int k = 0; k < 6; k++){
            float wv = iwT_s[pw][n][kb + k];
            acc[k][0] += v0 * wv;
            acc[k][1] += v1 * wv;
            acc[k][2] += v2 * wv;
        }
    }

    unsigned short* dst = Am + (size_t)m * KDIM + lane * AN;
    #pragma unroll
    for (int k = 0; k < 6; k++){
        s16x4 h0, h1, h2;
        #pragma unroll
        for (int j = 0; j < 4; j++){
            h0[j] = (short)f2bf(acc[k][0][j]);
            h1[j] = (short)f2bf(acc[k][1][j]);
            h2[j] = (short)f2bf(acc[k][2][j]);
        }
        s16x4* o = (s16x4*)(dst + (kb + k)*768);
        o[0] = h0; o[1] = h1; o[2] = h2;
    }
}

// ---------------- Kernel 4: GEMM 256x256, 8 waves, dbuf BK=64, counted vmcnt ----------------
// HK geometry: per-wave tile 128x64 (2M x 4N waves) -> 25% fewer LDS bytes/FLOP than 64x64.
// 1 block/CU but 8 waves = 2/SIMD (R9's 1-wave/SIMD failure avoided). 128 KB LDS dbuf.
// Sync skeleton identical to R8 (proven race-free): barrier -> ISSUE(s+1) -> vmcnt(8) ->
// barrier -> BODY(s). 8 loads/thread/batch stay in flight across the whole body.
// T2 swizzle: source chunk ch^(row&7), same XOR on read (involution; measured 0 conflicts).
// Split-K z=5, uneven: z0=32 steps, z1..4=31 steps (156 total); grid 16x3x5=240 blocks
// = one clean round on 256 CUs.
__global__ __launch_bounds__(512, 1) void k_gemm(const unsigned short* __restrict__ Am,
                                                 const unsigned short* __restrict__ Bm,
                                                 __half* __restrict__ part)
{
    __shared__ unsigned short Al[2][BM*BK];    // 2 x 32 KB
    __shared__ unsigned short Bl[2][BNT*BK];   // 2 x 32 KB
    int t = threadIdx.x;
    int lane = t & 63, w = t >> 6;
    int wr = w >> 2, wc = w & 3;               // 2M x 4N
    int l15 = lane & 15;
    int kofs = (lane >> 4) * 8;
    int m0 = blockIdx.x * BM, n0 = blockIdx.y * BNT;
    int z = blockIdx.z;
    int kstart = (z == 0) ? 0 : (32 + (z - 1) * 31);   // in BK units
    int nsteps = (z == 0) ? 32 : 31;
    int kbase = kstart * BK;

    // staging chunks: g = i*512 + t (i<4 for A, i<4 for B). row=g>>3, ch=g&7 (16B chunks).
    const unsigned short* gA[4];
    const unsigned short* gB[4];
    int lofsA[4], lofsB[4];
    #pragma unroll
    for (int i = 0; i < 4; i++){
        int g = i*512 + t;
        int row = g >> 3, ch = g & 7;
        int sch = ch ^ (row & 7);           // pre-swizzled source chunk (involution)
        gA[i] = Am + (size_t)(m0 + row) * KDIM + kbase + sch*8;
        gB[i] = Bm + (size_t)(n0 + row) * KDIM + kbase + sch*8;
        lofsA[i] = g * 8;
        lofsB[i] = g * 8;
    }

    f32x4 acc[8][4] = {};

#define ISSUE(S,KK) {                                                    \
        _Pragma("unroll")                                                \
        for (int i = 0; i < 4; i++) gload16(gA[i] + (KK), &Al[(S)&1][lofsA[i]]); \
        _Pragma("unroll")                                                \
        for (int i = 0; i < 4; i++) gload16(gB[i] + (KK), &Bl[(S)&1][lofsB[i]]); }

#define BODY(S) { const int cur_ = (S) & 1;                              \
        _Pragma("unroll")                                                \
        for (int kh = 0; kh < 2; kh++){                                  \
            int cc = kh*4 + (kofs >> 3);                                 \
            short8 af[8], bf[4];                                         \
            _Pragma("unroll")                                            \
            for (int i = 0; i < 8; i++){                                 \
                int ra = wr*128 + i*16 + l15;                            \
                af[i] = *(const short8*)&Al[cur_][ra*BK + ((cc ^ (ra & 7)) * 8)]; \
            }                                                            \
            _Pragma("unroll")                                            \
            for (int j = 0; j < 4; j++){                                 \
                int rb = wc*64 + j*16 + l15;                             \
                bf[j] = *(const short8*)&Bl[cur_][rb*BK + ((cc ^ (rb & 7)) * 8)]; \
            }                                                            \
            _Pragma("unroll")                                            \
            for (int i = 0; i < 8; i++){                                 \
                _Pragma("unroll")                                        \
                for (int j = 0; j < 4; j++)                              \
                    acc[i][j] = __builtin_amdgcn_mfma_f32_16x16x32_bf16(af[i], bf[j], acc[i][j], 0, 0, 0); \
            }                                                            \
        } }

    // prologue: stage tile 0 into buffer 0
    ISSUE(0, 0);

    for (int s = 0; s < nsteps; ++s){
        __builtin_amdgcn_s_barrier();            // WAR: all waves done reading buf[(s+1)&1]
        if (s + 1 < nsteps){
            ISSUE(s + 1, (s + 1) * BK);
            asm volatile("s_waitcnt vmcnt(8)" ::: "memory");
        } else {
            asm volatile("s_waitcnt vmcnt(0)" ::: "memory");
        }
        __builtin_amdgcn_s_barrier();            // RAW: every wave's batch-s loads landed
        BODY(s);
    }
#undef ISSUE
#undef BODY

    // epilogue: fp16 partials. C/D layout col=lane&15, row=(lane>>4)*4+q [m89-verified]
    __half* pp = part + (size_t)z * ((size_t)MDIM * NDIM);
    #pragma unroll
    for (int i = 0; i < 8; i++){
        #pragma unroll
        for (int j = 0; j < 4; j++){
            int col = n0 + wc*64 + j*16 + l15;
            #pragma unroll
            for (int q = 0; q < 4; q++){
                int row = m0 + wr*128 + i*16 + (lane >> 4)*4 + q;
                pp[(size_t)row * NDIM + col] = __float2half(acc[i][j][q]);
            }
        }
    }
}

// ---------------- Kernel 5: split-K reduce (fp16 partials) + scatter to bdpr ----------------
__global__ __launch_bounds__(256) void k_reduce(const __half* __restrict__ part,
                                                float* __restrict__ out)
{
    int t = blockIdx.x * 256 + threadIdx.x;        // per float4: MDIM*NDIM/4
    if (t >= MDIM * (NDIM/4)) return;
    int m = t / (NDIM/4);
    int n4 = (t - m * (NDIM/4)) * 4;
    f32x4 s = {};
    #pragma unroll
    for (int z = 0; z < NSPLIT; z++){
        const __half2* pz = (const __half2*)(part + (size_t)z * ((size_t)MDIM * NDIM) + (size_t)m * NDIM + n4);
        float2 a = __half22float2(pz[0]);
        float2 b = __half22float2(pz[1]);
        s[0] += a.x; s[1] += a.y; s[2] += b.x; s[3] += b.y;
    }
    int b = m >> 10, p = m & 1023;
    int d = n4 / AN, r = n4 - d*AN;    // r in {0,4,8}: never crosses d within 4
    *(f32x4*)(out + ((size_t)((b << 6) + d) * PN + p) * AN + r) = s;
}

extern "C" void kernel_launch(void* const* d_in, const int* in_sizes, int n_in,
                              void* d_out, int out_size, void* d_ws, size_t ws_size,
                              hipStream_t stream)
{
    const int*   nbr     = (const int*)  d_in[0];
    const float* vert    = (const float*)d_in[1];
    const float* fm      = (const float*)d_in[2];
    const float* W       = (const float*)d_in[3];
    const float* vs      = (const float*)d_in[4];
    const int*   idx_map = (const int*)  d_in[5];
    const int*   tiv     = (const int*)  d_in[6];
    const int*   tir     = (const int*)  d_in[7];
    float* out = (float*)d_out;

    char* ws = (char*)d_ws;
    float*          iw   = (float*)ws;                                  // 3,145,728 B
    unsigned short* Bm   = (unsigned short*)(ws + 3145728);             // 15,335,424 B
    unsigned short* Am   = (unsigned short*)(ws + 18481152);            // 81,788,928 B
    __half*         part = (__half*)(ws + 100270080);                   // 31,457,280 B (5 x fp16)

    k_prep   <<<5760, 256, 0, stream>>>(nbr, vert, vs, W, idx_map, tiv, tir, fm, iw, Bm, Am);
    k_newfeat<<<MDIM/2, 256, 0, stream>>>(nbr, iw, Am);
    dim3 g(MDIM/BM, NDIM/BNT, NSPLIT);
    k_gemm   <<<g, 512, 0, stream>>>(Am, Bm, part);
    k_reduce <<<(MDIM*(NDIM/4))/256, 256, 0, stream>>>(part, out);
}